// Round 5
// baseline (244.729 us; speedup 1.0000x reference)
//
#include <hip/hip_runtime.h>
#include <stdint.h>

// MFMA fragment types (gfx950)
typedef __attribute__((ext_vector_type(8))) short short8;  // 8 bf16 = 4 VGPRs
typedef __attribute__((ext_vector_type(4))) float f32x4;   // 4 fp32 acc / vec load

static_assert(sizeof(short8) == 16, "frag size");

__device__ __forceinline__ uint16_t f2bf(float f) {
  uint32_t u = __builtin_bit_cast(uint32_t, f);
  u += 0x7fffu + ((u >> 16) & 1u);
  return (uint16_t)(u >> 16);
}

__device__ __forceinline__ void gload_lds16(const void* g, void* lds_wave_base) {
  // async global->LDS, 16B/lane; LDS dst = wave-uniform base + lane*16
  __builtin_amdgcn_global_load_lds(
      (__attribute__((address_space(1))) void*)(void*)(g),
      (__attribute__((address_space(3))) void*)(lds_wave_base),
      16, 0, 0);
}

// Swizzle convention (all bf16 staging): within each 64-elem K-group, 16B
// chunk c of row r is stored at chunk c ^ (r&7). DMA stages tiles verbatim;
// fragment reads at chunk (h*4+q)^(r&7) are conflict-free ds_read_b128.

// ---------------------------------------------------------------------------
// quant: dwT[o][i] = ternary(weight[i][o]) in {-1,0,+1} bf16, swizzled.
// ---------------------------------------------------------------------------
__global__ __launch_bounds__(256) void quant_kernel(const float* __restrict__ w,
                                                    uint16_t* __restrict__ dwT) {
  const int o = blockIdx.x, i = threadIdx.x;
  const float v = w[i * 256 + o];
  const float t = (v > 0.01f) ? 1.0f : ((v < -0.01f) ? -1.0f : 0.0f);
  dwT[o * 256 + (i ^ ((o & 7) << 3))] = f2bf(t);
}

// ---------------------------------------------------------------------------
// support: spt[o][g] = bf16(0.01 * sum_i x[g][i] * tern[i][o]), swizzled cols.
// Tile [128 g][64 o], K=256 (BK=64). 512 blocks x 256 thr.
// Block remap: the 4 o-sibling tiles of one g-tile share bIdx&7 so they land
// on the same XCD (round-robin dispatch) -> x rows fetched once per XCD.
// ---------------------------------------------------------------------------
#define SB_A 0       // [128][64] bf16 swizzled, 16384 B (reused in epilogue)
#define SB_B 16384   // [64][64] bf16, 8192 B

__global__ __launch_bounds__(256) void support_kernel(const float* __restrict__ x,
                                                      const uint16_t* __restrict__ dwT,
                                                      uint16_t* __restrict__ spt) {
  __shared__ __align__(16) unsigned char smem[24576];
  const int t = threadIdx.x, lane = t & 63, w = t >> 6;
  const int r = lane & 15, q = lane >> 4;
  // XCD co-location: gt = bIdx&7 | (bIdx>>5)<<3 (7 bits), ot = (bIdx>>3)&3
  const int gt = (blockIdx.x & 7) | ((blockIdx.x >> 5) << 3);
  const int g0 = gt * 128;
  const int o0 = ((blockIdx.x >> 3) & 3) * 64;

  f32x4 acc[2][4] = {};

  for (int k0 = 0; k0 < 256; k0 += 64) {
#pragma unroll
    for (int it = 0; it < 4; ++it) {
      const int id = it * 256 + t, row = id >> 3, c = id & 7;
      const float* p = x + (size_t)(g0 + row) * 256 + k0 + c * 8;
      const f32x4 v0 = *(const f32x4*)p;
      const f32x4 v1 = *(const f32x4*)(p + 4);
      uint4 u;
      u.x = (uint32_t)f2bf(v0.x) | ((uint32_t)f2bf(v0.y) << 16);
      u.y = (uint32_t)f2bf(v0.z) | ((uint32_t)f2bf(v0.w) << 16);
      u.z = (uint32_t)f2bf(v1.x) | ((uint32_t)f2bf(v1.y) << 16);
      u.w = (uint32_t)f2bf(v1.z) | ((uint32_t)f2bf(v1.w) << 16);
      *(uint4*)(smem + SB_A + row * 128 + ((c ^ (row & 7)) << 4)) = u;
    }
#pragma unroll
    for (int j = 0; j < 2; ++j) {
      const int id = j * 256 + t, row = id >> 3, c = id & 7;
      gload_lds16(dwT + (size_t)(o0 + row) * 256 + k0 + c * 8,
                  smem + SB_B + (size_t)(j * 256 + w * 64) * 16);
    }
    __syncthreads();
#pragma unroll
    for (int h = 0; h < 2; ++h) {
      short8 av[2], bv[4];
      const int pc = (((h * 4 + q) ^ (r & 7)) << 4);
#pragma unroll
      for (int mi = 0; mi < 2; ++mi)
        av[mi] = *(const short8*)(smem + SB_A + (32 * w + 16 * mi + r) * 128 + pc);
#pragma unroll
      for (int ni = 0; ni < 4; ++ni)
        bv[ni] = *(const short8*)(smem + SB_B + (16 * ni + r) * 128 + pc);
#pragma unroll
      for (int mi = 0; mi < 2; ++mi)
#pragma unroll
        for (int ni = 0; ni < 4; ++ni)
          acc[mi][ni] = __builtin_amdgcn_mfma_f32_16x16x32_bf16(av[mi], bv[ni],
                                                                acc[mi][ni], 0, 0, 0);
    }
    __syncthreads();
  }
  // epilogue: LDS transpose -> coalesced dwordx4 stores of spt rows
#pragma unroll
  for (int ni = 0; ni < 4; ++ni) {
    const int ol = 16 * ni + r;
#pragma unroll
    for (int mi = 0; mi < 2; ++mi)
#pragma unroll
      for (int reg = 0; reg < 4; ++reg) {
        const int gl = 32 * w + 16 * mi + 4 * q + reg;      // C row = g
        const int gsw = gl ^ ((ol & 7) << 3);               // global col swizzle
        *(uint16_t*)(smem + (ol * 128 + gsw) * 2) = f2bf(acc[mi][ni][reg] * 0.01f);
      }
  }
  __syncthreads();
#pragma unroll
  for (int it = 0; it < 4; ++it) {
    const int id = it * 256 + t, row = id >> 4, cc = id & 15;
    const uint4 u = *(const uint4*)(smem + (row * 128 + cc * 8) * 2);
    *(uint4*)(spt + (size_t)(o0 + row) * 16384 + g0 + cc * 8) = u;
  }
}

// ---------------------------------------------------------------------------
// main (fused convert): out[b][n][o] = relu(sum_m adj[b,n,m]*spt[o][b,m] + bias[o])
// Tile [32 n][256 o], K=2048 (BK=64). Grid 512 = 8 bb x 64 n-tiles -> o-split=1,
// adj fp32 read EXACTLY ONCE from HBM via NON-TEMPORAL loads (134 MB single-use
// stream must not evict the L2-resident spt[bb] slice). out stores also nt.
// B = spt staged verbatim via global_load_lds (pre-swizzled). Wave w owns
// o-slice [64w, 64w+64): acc[2][4] (n x o). HBM-BW-bound: dbuf tried R4, neutral.
// ---------------------------------------------------------------------------
#define MB_A 0       // [32][64] bf16 swizzled, 4096 B
#define MB_B 4096    // [256][64] bf16, 32768 B

__global__ __launch_bounds__(256) void gcn_main_kernel(const float* __restrict__ adj,
                                                       const uint16_t* __restrict__ spt,
                                                       const float* __restrict__ bias,
                                                       float* __restrict__ out) {
  __shared__ __align__(16) unsigned char smem[36864];
  const int t = threadIdx.x, lane = t & 63, w = t >> 6;
  const int r = lane & 15, q = lane >> 4;
  const int bb = blockIdx.x & 7;             // batch -> XCD affinity (spt[bb] L2-resident)
  const int n0 = (blockIdx.x >> 3) * 32;     // n-tile
  const float* adjb = adj + ((size_t)bb * 2048 + n0) * 2048;
  const uint16_t* sptb = spt + (size_t)bb * 2048;

  f32x4 acc[2][4] = {};

  for (int k0 = 0; k0 < 2048; k0 += 64) {
    // A: adj tile [32 n][64 m] fp32 -> bf16, nt loads, packed b128 swizzled write
    {
      const int row = t >> 3, c = t & 7;     // 32 rows x 8 chunks = 256 ids
      const float* p = adjb + (size_t)row * 2048 + k0 + c * 8;
      const f32x4 v0 = __builtin_nontemporal_load((const f32x4*)p);
      const f32x4 v1 = __builtin_nontemporal_load((const f32x4*)(p + 4));
      uint4 u;
      u.x = (uint32_t)f2bf(v0.x) | ((uint32_t)f2bf(v0.y) << 16);
      u.y = (uint32_t)f2bf(v0.z) | ((uint32_t)f2bf(v0.w) << 16);
      u.z = (uint32_t)f2bf(v1.x) | ((uint32_t)f2bf(v1.y) << 16);
      u.w = (uint32_t)f2bf(v1.z) | ((uint32_t)f2bf(v1.w) << 16);
      *(uint4*)(smem + MB_A + row * 128 + ((c ^ (row & 7)) << 4)) = u;
    }
    // B: spt tile [256 o][64 m], verbatim DMA
#pragma unroll
    for (int j = 0; j < 8; ++j) {
      const int id = j * 256 + t, row = id >> 3, c = id & 7;
      gload_lds16(sptb + (size_t)row * 16384 + k0 + c * 8,
                  smem + MB_B + (size_t)(j * 256 + w * 64) * 16);
    }
    __syncthreads();
#pragma unroll
    for (int h = 0; h < 2; ++h) {
      short8 av[2], bv[4];
      const int pc = (((h * 4 + q) ^ (r & 7)) << 4);
#pragma unroll
      for (int mi = 0; mi < 2; ++mi)
        av[mi] = *(const short8*)(smem + MB_A + (16 * mi + r) * 128 + pc);
#pragma unroll
      for (int ni = 0; ni < 4; ++ni)
        bv[ni] = *(const short8*)(smem + MB_B + (w * 64 + 16 * ni + r) * 128 + pc);
#pragma unroll
      for (int mi = 0; mi < 2; ++mi)
#pragma unroll
        for (int ni = 0; ni < 4; ++ni)
          acc[mi][ni] = __builtin_amdgcn_mfma_f32_16x16x32_bf16(av[mi], bv[ni],
                                                                acc[mi][ni], 0, 0, 0);
    }
    __syncthreads();
  }
  // epilogue: +bias, relu, fp32 nt store (out is write-once)
#pragma unroll
  for (int ni = 0; ni < 4; ++ni) {
    const int o = w * 64 + 16 * ni + r;      // C col = N = o
    const float bs = bias[o];
#pragma unroll
    for (int mi = 0; mi < 2; ++mi)
#pragma unroll
      for (int reg = 0; reg < 4; ++reg) {
        const int n = n0 + 16 * mi + 4 * q + reg;  // C row = M = n
        __builtin_nontemporal_store(fmaxf(acc[mi][ni][reg] + bs, 0.0f),
                                    out + ((size_t)bb * 2048 + n) * 256 + o);
      }
  }
}

// ---------------------------------------------------------------------------
extern "C" void kernel_launch(void* const* d_in, const int* in_sizes, int n_in,
                              void* d_out, int out_size, void* d_ws, size_t ws_size,
                              hipStream_t stream) {
  const float* x      = (const float*)d_in[0];  // [8,2048,256]
  const float* adj    = (const float*)d_in[1];  // [8,2048,2048]
  const float* weight = (const float*)d_in[2];  // [256,256]
  const float* bias   = (const float*)d_in[3];  // [256]
  float* out = (float*)d_out;                   // [8,2048,256]

  uint16_t* dwT = (uint16_t*)d_ws;                          // 128 KB
  uint16_t* spt = (uint16_t*)((char*)d_ws + 131072);        // 8 MB

  hipLaunchKernelGGL(quant_kernel,    dim3(256), dim3(256), 0, stream, weight, dwT);
  hipLaunchKernelGGL(support_kernel,  dim3(512), dim3(256), 0, stream, x, dwT, spt);
  hipLaunchKernelGGL(gcn_main_kernel, dim3(512), dim3(256), 0, stream, adj, spt, bias, out);
}

// Round 6
// 231.381 us; speedup vs baseline: 1.0577x; 1.0577x over previous
//
#include <hip/hip_runtime.h>
#include <stdint.h>

// MFMA fragment types (gfx950)
typedef __attribute__((ext_vector_type(8))) short short8;  // 8 bf16 = 4 VGPRs
typedef __attribute__((ext_vector_type(4))) float f32x4;   // 4 fp32 acc / vec load

static_assert(sizeof(short8) == 16, "frag size");

__device__ __forceinline__ uint16_t f2bf(float f) {
  uint32_t u = __builtin_bit_cast(uint32_t, f);
  u += 0x7fffu + ((u >> 16) & 1u);
  return (uint16_t)(u >> 16);
}

__device__ __forceinline__ void gload_lds16(const void* g, void* lds_wave_base) {
  // async global->LDS, 16B/lane; LDS dst = wave-uniform base + lane*16
  __builtin_amdgcn_global_load_lds(
      (__attribute__((address_space(1))) void*)(void*)(g),
      (__attribute__((address_space(3))) void*)(lds_wave_base),
      16, 0, 0);
}

// Swizzle convention (all bf16 staging): within each 64-elem K-group, 16B
// chunk c of row r is stored at chunk c ^ (r&7) (XOR touches bits 0-2 only,
// so it composes transparently with multi-group BK=128 rows). DMA stages
// tiles verbatim; fragment reads at chunk (h*4+q)^(r&7) are conflict-free.

// ---------------------------------------------------------------------------
// quant: dwT[o][i] = ternary(weight[i][o]) in {-1,0,+1} bf16, swizzled.
// ---------------------------------------------------------------------------
__global__ __launch_bounds__(256) void quant_kernel(const float* __restrict__ w,
                                                    uint16_t* __restrict__ dwT) {
  const int o = blockIdx.x, i = threadIdx.x;
  const float v = w[i * 256 + o];
  const float t = (v > 0.01f) ? 1.0f : ((v < -0.01f) ? -1.0f : 0.0f);
  dwT[o * 256 + (i ^ ((o & 7) << 3))] = f2bf(t);
}

// ---------------------------------------------------------------------------
// support: spt[o][g] = bf16(0.01 * sum_i x[g][i] * tern[i][o]), swizzled cols.
// Tile [128 g][64 o], K=256 (BK=64). 512 blocks x 256 thr. (R3 exact — the
// R5 XCD remap regressed; x re-reads are L3-served anyway.)
// ---------------------------------------------------------------------------
#define SB_A 0       // [128][64] bf16 swizzled, 16384 B (reused in epilogue)
#define SB_B 16384   // [64][64] bf16, 8192 B

__global__ __launch_bounds__(256) void support_kernel(const float* __restrict__ x,
                                                      const uint16_t* __restrict__ dwT,
                                                      uint16_t* __restrict__ spt) {
  __shared__ __align__(16) unsigned char smem[24576];
  const int t = threadIdx.x, lane = t & 63, w = t >> 6;
  const int r = lane & 15, q = lane >> 4;
  const int g0 = (blockIdx.x & 127) * 128;
  const int o0 = (blockIdx.x >> 7) * 64;

  f32x4 acc[2][4] = {};

  for (int k0 = 0; k0 < 256; k0 += 64) {
#pragma unroll
    for (int it = 0; it < 4; ++it) {
      const int id = it * 256 + t, row = id >> 3, c = id & 7;
      const float* p = x + (size_t)(g0 + row) * 256 + k0 + c * 8;
      const f32x4 v0 = *(const f32x4*)p;
      const f32x4 v1 = *(const f32x4*)(p + 4);
      uint4 u;
      u.x = (uint32_t)f2bf(v0.x) | ((uint32_t)f2bf(v0.y) << 16);
      u.y = (uint32_t)f2bf(v0.z) | ((uint32_t)f2bf(v0.w) << 16);
      u.z = (uint32_t)f2bf(v1.x) | ((uint32_t)f2bf(v1.y) << 16);
      u.w = (uint32_t)f2bf(v1.z) | ((uint32_t)f2bf(v1.w) << 16);
      *(uint4*)(smem + SB_A + row * 128 + ((c ^ (row & 7)) << 4)) = u;
    }
#pragma unroll
    for (int j = 0; j < 2; ++j) {
      const int id = j * 256 + t, row = id >> 3, c = id & 7;
      gload_lds16(dwT + (size_t)(o0 + row) * 256 + k0 + c * 8,
                  smem + SB_B + (size_t)(j * 256 + w * 64) * 16);
    }
    __syncthreads();
#pragma unroll
    for (int h = 0; h < 2; ++h) {
      short8 av[2], bv[4];
      const int pc = (((h * 4 + q) ^ (r & 7)) << 4);
#pragma unroll
      for (int mi = 0; mi < 2; ++mi)
        av[mi] = *(const short8*)(smem + SB_A + (32 * w + 16 * mi + r) * 128 + pc);
#pragma unroll
      for (int ni = 0; ni < 4; ++ni)
        bv[ni] = *(const short8*)(smem + SB_B + (16 * ni + r) * 128 + pc);
#pragma unroll
      for (int mi = 0; mi < 2; ++mi)
#pragma unroll
        for (int ni = 0; ni < 4; ++ni)
          acc[mi][ni] = __builtin_amdgcn_mfma_f32_16x16x32_bf16(av[mi], bv[ni],
                                                                acc[mi][ni], 0, 0, 0);
    }
    __syncthreads();
  }
  // epilogue: LDS transpose -> coalesced dwordx4 stores of spt rows
#pragma unroll
  for (int ni = 0; ni < 4; ++ni) {
    const int ol = 16 * ni + r;
#pragma unroll
    for (int mi = 0; mi < 2; ++mi)
#pragma unroll
      for (int reg = 0; reg < 4; ++reg) {
        const int gl = 32 * w + 16 * mi + 4 * q + reg;      // C row = g
        const int gsw = gl ^ ((ol & 7) << 3);               // global col swizzle
        *(uint16_t*)(smem + (ol * 128 + gsw) * 2) = f2bf(acc[mi][ni][reg] * 0.01f);
      }
  }
  __syncthreads();
#pragma unroll
  for (int it = 0; it < 4; ++it) {
    const int id = it * 256 + t, row = id >> 4, cc = id & 15;
    const uint4 u = *(const uint4*)(smem + (row * 128 + cc * 8) * 2);
    *(uint4*)(spt + (size_t)(o0 + row) * 16384 + g0 + cc * 8) = u;
  }
}

// ---------------------------------------------------------------------------
// main (fused convert, BK=128): out = relu(adj @ support + bias)
// Tile [32 n][256 o], K=2048 in BK=128 steps (16 iters, half the barriers of
// R3). Grid 512 = 8 bb x 64 n-tiles -> o-split=1, adj fp32 read exactly once.
// LDS 72 KB/stage -> 2 blocks/CU (same as R3; barrier count halved).
// nt hints removed (R5: neutral/regressed — kernel is HBM-BW-bound on adj).
// ---------------------------------------------------------------------------
#define MB_A 0       // [32][128] bf16 swizzled, 8192 B
#define MB_B 8192    // [256][128] bf16, 65536 B

__global__ __launch_bounds__(256) void gcn_main_kernel(const float* __restrict__ adj,
                                                       const uint16_t* __restrict__ spt,
                                                       const float* __restrict__ bias,
                                                       float* __restrict__ out) {
  __shared__ __align__(16) unsigned char smem[73728];
  const int t = threadIdx.x, lane = t & 63, w = t >> 6;
  const int r = lane & 15, q = lane >> 4;
  const int bb = blockIdx.x & 7;             // batch -> XCD affinity (spt[bb] L2-resident)
  const int n0 = (blockIdx.x >> 3) * 32;     // n-tile
  const float* adjb = adj + ((size_t)bb * 2048 + n0) * 2048;
  const uint16_t* sptb = spt + (size_t)bb * 2048;

  f32x4 acc[2][4] = {};

  for (int k0 = 0; k0 < 2048; k0 += 128) {
    // A: adj tile [32 n][128 m] fp32 -> bf16, packed b128 swizzled writes
#pragma unroll
    for (int it = 0; it < 2; ++it) {
      const int id = it * 256 + t;           // 32 rows x 16 chunks = 512 ids
      const int row = id >> 4, c = id & 15;
      const float* p = adjb + (size_t)row * 2048 + k0 + c * 8;
      const f32x4 v0 = *(const f32x4*)p;
      const f32x4 v1 = *(const f32x4*)(p + 4);
      uint4 u;
      u.x = (uint32_t)f2bf(v0.x) | ((uint32_t)f2bf(v0.y) << 16);
      u.y = (uint32_t)f2bf(v0.z) | ((uint32_t)f2bf(v0.w) << 16);
      u.z = (uint32_t)f2bf(v1.x) | ((uint32_t)f2bf(v1.y) << 16);
      u.w = (uint32_t)f2bf(v1.z) | ((uint32_t)f2bf(v1.w) << 16);
      *(uint4*)(smem + MB_A + row * 256 + ((c ^ (row & 7)) << 4)) = u;
    }
    // B: spt tile [256 o][128 m], verbatim DMA (16 chunks/row)
#pragma unroll
    for (int j = 0; j < 16; ++j) {
      const int id = j * 256 + t, row = id >> 4, c = id & 15;
      gload_lds16(sptb + (size_t)row * 16384 + k0 + c * 8,
                  smem + MB_B + (size_t)(j * 256 + w * 64) * 16);
    }
    __syncthreads();
#pragma unroll
    for (int h = 0; h < 4; ++h) {            // 4 k-halves of 32 each
      short8 av[2], bv[4];
      const int pc = (((h * 4 + q) ^ (r & 7)) << 4);  // XOR stays in low 3 bits
#pragma unroll
      for (int mi = 0; mi < 2; ++mi)
        av[mi] = *(const short8*)(smem + MB_A + (16 * mi + r) * 256 + pc);
#pragma unroll
      for (int ni = 0; ni < 4; ++ni)
        bv[ni] = *(const short8*)(smem + MB_B + (w * 64 + 16 * ni + r) * 256 + pc);
#pragma unroll
      for (int mi = 0; mi < 2; ++mi)
#pragma unroll
        for (int ni = 0; ni < 4; ++ni)
          acc[mi][ni] = __builtin_amdgcn_mfma_f32_16x16x32_bf16(av[mi], bv[ni],
                                                                acc[mi][ni], 0, 0, 0);
    }
    __syncthreads();
  }
  // epilogue: +bias, relu, fp32 store
#pragma unroll
  for (int ni = 0; ni < 4; ++ni) {
    const int o = w * 64 + 16 * ni + r;      // C col = N = o
    const float bs = bias[o];
#pragma unroll
    for (int mi = 0; mi < 2; ++mi)
#pragma unroll
      for (int reg = 0; reg < 4; ++reg) {
        const int n = n0 + 16 * mi + 4 * q + reg;  // C row = M = n
        out[((size_t)bb * 2048 + n) * 256 + o] = fmaxf(acc[mi][ni][reg] + bs, 0.0f);
      }
  }
}

// ---------------------------------------------------------------------------
extern "C" void kernel_launch(void* const* d_in, const int* in_sizes, int n_in,
                              void* d_out, int out_size, void* d_ws, size_t ws_size,
                              hipStream_t stream) {
  const float* x      = (const float*)d_in[0];  // [8,2048,256]
  const float* adj    = (const float*)d_in[1];  // [8,2048,2048]
  const float* weight = (const float*)d_in[2];  // [256,256]
  const float* bias   = (const float*)d_in[3];  // [256]
  float* out = (float*)d_out;                   // [8,2048,256]

  uint16_t* dwT = (uint16_t*)d_ws;                          // 128 KB
  uint16_t* spt = (uint16_t*)((char*)d_ws + 131072);        // 8 MB

  hipLaunchKernelGGL(quant_kernel,    dim3(256), dim3(256), 0, stream, weight, dwT);
  hipLaunchKernelGGL(support_kernel,  dim3(512), dim3(256), 0, stream, x, dwT, spt);
  hipLaunchKernelGGL(gcn_main_kernel, dim3(512), dim3(256), 0, stream, adj, spt, bias, out);
}

// Round 7
// 229.731 us; speedup vs baseline: 1.0653x; 1.0072x over previous
//
#include <hip/hip_runtime.h>
#include <stdint.h>

// MFMA fragment types (gfx950)
typedef __attribute__((ext_vector_type(8))) short short8;  // 8 bf16 = 4 VGPRs
typedef __attribute__((ext_vector_type(4))) float f32x4;   // 4 fp32 acc / vec load

static_assert(sizeof(short8) == 16, "frag size");

__device__ __forceinline__ uint16_t f2bf(float f) {
  uint32_t u = __builtin_bit_cast(uint32_t, f);
  u += 0x7fffu + ((u >> 16) & 1u);
  return (uint16_t)(u >> 16);
}

__device__ __forceinline__ void gload_lds16(const void* g, void* lds_wave_base) {
  // async global->LDS, 16B/lane; LDS dst = wave-uniform base + lane*16
  __builtin_amdgcn_global_load_lds(
      (__attribute__((address_space(1))) void*)(void*)(g),
      (__attribute__((address_space(3))) void*)(lds_wave_base),
      16, 0, 0);
}

// Swizzle convention (all bf16 staging): within each 64-elem K-group, 16B
// chunk c of row r is stored at chunk c ^ (r&7) (XOR touches bits 0-2 only,
// composing transparently with any BK). DMA stages tiles verbatim; fragment
// reads at chunk (h*4+q)^(r&7) are conflict-free ds_read_b128.

// ---------------------------------------------------------------------------
// quant: dwT[o][i] = ternary(weight[i][o]) in {-1,0,+1} bf16, swizzled.
// ---------------------------------------------------------------------------
__global__ __launch_bounds__(256) void quant_kernel(const float* __restrict__ w,
                                                    uint16_t* __restrict__ dwT) {
  const int o = blockIdx.x, i = threadIdx.x;
  const float v = w[i * 256 + o];
  const float t = (v > 0.01f) ? 1.0f : ((v < -0.01f) ? -1.0f : 0.0f);
  dwT[o * 256 + (i ^ ((o & 7) << 3))] = f2bf(t);
}

// ---------------------------------------------------------------------------
// support (SINGLE-PASS K=256): spt[o][g] = bf16(0.01 * sum_i x[g][i]*tern[i][o])
// Tile [64 g][64 o], full K staged once (A 32 KB + B 32 KB = 64 KB LDS,
// 2 blocks/CU). Grid 1024 = 256 g-tiles x 4 o-tiles. 3 barriers/block total
// (vs 8 in the R3 K-loop shape — R6 showed barrier drain is a real cost).
// Wave w: g-rows [16w,16w+16) -> acc[4] (o-tiles).
// ---------------------------------------------------------------------------
#define SB_A 0       // [64 g][256 i] bf16 swizzled, 32768 B (reused in epilogue)
#define SB_B 32768   // [64 o][256 i] bf16 swizzled, 32768 B

__global__ __launch_bounds__(256) void support_kernel(const float* __restrict__ x,
                                                      const uint16_t* __restrict__ dwT,
                                                      uint16_t* __restrict__ spt) {
  __shared__ __align__(16) unsigned char smem[65536];
  const int t = threadIdx.x, lane = t & 63, w = t >> 6;
  const int r = lane & 15, q = lane >> 4;
  const int g0 = (blockIdx.x & 255) * 64;
  const int o0 = (blockIdx.x >> 8) * 64;

  // stage A: x [64 g][256 i] fp32 -> bf16, packed b128 swizzled writes
#pragma unroll
  for (int j = 0; j < 8; ++j) {
    const int id = j * 256 + t;              // 64 rows x 32 chunks = 2048 ids
    const int row = id >> 5, c = id & 31;
    const float* p = x + (size_t)(g0 + row) * 256 + c * 8;
    const f32x4 v0 = *(const f32x4*)p;
    const f32x4 v1 = *(const f32x4*)(p + 4);
    uint4 u;
    u.x = (uint32_t)f2bf(v0.x) | ((uint32_t)f2bf(v0.y) << 16);
    u.y = (uint32_t)f2bf(v0.z) | ((uint32_t)f2bf(v0.w) << 16);
    u.z = (uint32_t)f2bf(v1.x) | ((uint32_t)f2bf(v1.y) << 16);
    u.w = (uint32_t)f2bf(v1.z) | ((uint32_t)f2bf(v1.w) << 16);
    *(uint4*)(smem + SB_A + row * 512 + ((c ^ (row & 7)) << 4)) = u;
  }
  // stage B: dwT rows [o0,o0+64) full K, verbatim DMA (pre-swizzled)
#pragma unroll
  for (int j = 0; j < 8; ++j) {
    const int id = j * 256 + t, row = id >> 5, c = id & 31;
    gload_lds16(dwT + (size_t)(o0 + row) * 256 + c * 8,
                smem + SB_B + (size_t)(j * 256 + w * 64) * 16);
  }
  __syncthreads();

  f32x4 acc[4] = {};
#pragma unroll
  for (int h = 0; h < 8; ++h) {              // K=256 in 8 steps of 32
    short8 av, bv[4];
    const int pc = (((h * 4 + q) ^ (r & 7)) << 4);
    av = *(const short8*)(smem + SB_A + (16 * w + r) * 512 + pc);
#pragma unroll
    for (int ni = 0; ni < 4; ++ni)
      bv[ni] = *(const short8*)(smem + SB_B + (16 * ni + r) * 512 + pc);
#pragma unroll
    for (int ni = 0; ni < 4; ++ni)
      acc[ni] = __builtin_amdgcn_mfma_f32_16x16x32_bf16(av, bv[ni], acc[ni], 0, 0, 0);
  }
  __syncthreads();   // all waves' LDS reads done before transpose overwrite

  // epilogue: transpose buffer [64 o][64 g] bf16 (8 KB, reuses SB_A region)
#pragma unroll
  for (int ni = 0; ni < 4; ++ni) {
    const int ol = 16 * ni + r;              // C col = o
#pragma unroll
    for (int reg = 0; reg < 4; ++reg) {
      const int gl = 16 * w + 4 * q + reg;   // C row = g
      const int gsw = gl ^ ((ol & 7) << 3);  // global col swizzle
      *(uint16_t*)(smem + (ol * 64 + gsw) * 2) = f2bf(acc[ni][reg] * 0.01f);
    }
  }
  __syncthreads();
  // copy out: 64 rows x 8 chunks of 16 B, coalesced dwordx4
#pragma unroll
  for (int it = 0; it < 2; ++it) {
    const int id = it * 256 + t, row = id >> 3, cc = id & 7;
    const uint4 u = *(const uint4*)(smem + (row * 64 + cc * 8) * 2);
    *(uint4*)(spt + (size_t)(o0 + row) * 16384 + g0 + cc * 8) = u;
  }
}

// ---------------------------------------------------------------------------
// main (fused convert, BK=128): out = relu(adj @ support + bias)
// Tile [32 n][256 o], K=2048 in BK=128 steps (16 iters). Grid 512 = 8 bb x 64
// n-tiles -> o-split=1, adj fp32 read exactly once. LDS 72 KB -> 2 blocks/CU.
// (R6 verified win: halved barriers vs BK=64. R4 dbuf / R5 nt: neutral/regressed.)
// ---------------------------------------------------------------------------
#define MB_A 0       // [32][128] bf16 swizzled, 8192 B
#define MB_B 8192    // [256][128] bf16, 65536 B

__global__ __launch_bounds__(256) void gcn_main_kernel(const float* __restrict__ adj,
                                                       const uint16_t* __restrict__ spt,
                                                       const float* __restrict__ bias,
                                                       float* __restrict__ out) {
  __shared__ __align__(16) unsigned char smem[73728];
  const int t = threadIdx.x, lane = t & 63, w = t >> 6;
  const int r = lane & 15, q = lane >> 4;
  const int bb = blockIdx.x & 7;             // batch -> XCD affinity (spt[bb] L2-resident)
  const int n0 = (blockIdx.x >> 3) * 32;     // n-tile
  const float* adjb = adj + ((size_t)bb * 2048 + n0) * 2048;
  const uint16_t* sptb = spt + (size_t)bb * 2048;

  f32x4 acc[2][4] = {};

  for (int k0 = 0; k0 < 2048; k0 += 128) {
    // A: adj tile [32 n][128 m] fp32 -> bf16, packed b128 swizzled writes
#pragma unroll
    for (int it = 0; it < 2; ++it) {
      const int id = it * 256 + t;           // 32 rows x 16 chunks = 512 ids
      const int row = id >> 4, c = id & 15;
      const float* p = adjb + (size_t)row * 2048 + k0 + c * 8;
      const f32x4 v0 = *(const f32x4*)p;
      const f32x4 v1 = *(const f32x4*)(p + 4);
      uint4 u;
      u.x = (uint32_t)f2bf(v0.x) | ((uint32_t)f2bf(v0.y) << 16);
      u.y = (uint32_t)f2bf(v0.z) | ((uint32_t)f2bf(v0.w) << 16);
      u.z = (uint32_t)f2bf(v1.x) | ((uint32_t)f2bf(v1.y) << 16);
      u.w = (uint32_t)f2bf(v1.z) | ((uint32_t)f2bf(v1.w) << 16);
      *(uint4*)(smem + MB_A + row * 256 + ((c ^ (row & 7)) << 4)) = u;
    }
    // B: spt tile [256 o][128 m], verbatim DMA (16 chunks/row)
#pragma unroll
    for (int j = 0; j < 16; ++j) {
      const int id = j * 256 + t, row = id >> 4, c = id & 15;
      gload_lds16(sptb + (size_t)row * 16384 + k0 + c * 8,
                  smem + MB_B + (size_t)(j * 256 + w * 64) * 16);
    }
    __syncthreads();
#pragma unroll
    for (int h = 0; h < 4; ++h) {            // 4 k-halves of 32 each
      short8 av[2], bv[4];
      const int pc = (((h * 4 + q) ^ (r & 7)) << 4);  // XOR stays in low 3 bits
#pragma unroll
      for (int mi = 0; mi < 2; ++mi)
        av[mi] = *(const short8*)(smem + MB_A + (16 * mi + r) * 256 + pc);
#pragma unroll
      for (int ni = 0; ni < 4; ++ni)
        bv[ni] = *(const short8*)(smem + MB_B + (w * 64 + 16 * ni + r) * 256 + pc);
#pragma unroll
      for (int mi = 0; mi < 2; ++mi)
#pragma unroll
        for (int ni = 0; ni < 4; ++ni)
          acc[mi][ni] = __builtin_amdgcn_mfma_f32_16x16x32_bf16(av[mi], bv[ni],
                                                                acc[mi][ni], 0, 0, 0);
    }
    __syncthreads();
  }
  // epilogue: +bias, relu, fp32 store
#pragma unroll
  for (int ni = 0; ni < 4; ++ni) {
    const int o = w * 64 + 16 * ni + r;      // C col = N = o
    const float bs = bias[o];
#pragma unroll
    for (int mi = 0; mi < 2; ++mi)
#pragma unroll
      for (int reg = 0; reg < 4; ++reg) {
        const int n = n0 + 16 * mi + 4 * q + reg;  // C row = M = n
        out[((size_t)bb * 2048 + n) * 256 + o] = fmaxf(acc[mi][ni][reg] + bs, 0.0f);
      }
  }
}

// ---------------------------------------------------------------------------
extern "C" void kernel_launch(void* const* d_in, const int* in_sizes, int n_in,
                              void* d_out, int out_size, void* d_ws, size_t ws_size,
                              hipStream_t stream) {
  const float* x      = (const float*)d_in[0];  // [8,2048,256]
  const float* adj    = (const float*)d_in[1];  // [8,2048,2048]
  const float* weight = (const float*)d_in[2];  // [256,256]
  const float* bias   = (const float*)d_in[3];  // [256]
  float* out = (float*)d_out;                   // [8,2048,256]

  uint16_t* dwT = (uint16_t*)d_ws;                          // 128 KB
  uint16_t* spt = (uint16_t*)((char*)d_ws + 131072);        // 8 MB

  hipLaunchKernelGGL(quant_kernel,    dim3(256),  dim3(256), 0, stream, weight, dwT);
  hipLaunchKernelGGL(support_kernel,  dim3(1024), dim3(256), 0, stream, x, dwT, spt);
  hipLaunchKernelGGL(gcn_main_kernel, dim3(512),  dim3(256), 0, stream, adj, spt, bias, out);
}